// Round 5
// baseline (292.627 us; speedup 1.0000x reference)
//
#include <hip/hip_runtime.h>

#define GRID 2048
#define BLK  256
#define NWAVES (BLK / 64)
#define STRIDE (GRID * BLK)

// Native clang vector type — __builtin_nontemporal_load needs this.
typedef float floatx4 __attribute__((ext_vector_type(4)));

__device__ __forceinline__ float frcp(float x) {
    return __builtin_amdgcn_rcpf(x);
}

__device__ __forceinline__ float sqd1(floatx4 p) {
    float dx = p.x - p.z, dy = p.y - p.w;
    return fmaf(dx, dx, fmaf(dy, dy, 1.0f));
}

// Merged three-stream loop: every iteration issues 7 independent loads
// (2 nb + 1 mn + 4 fr, matching the 2:1:4 element ratio) so each wave keeps
// ~7 KB in flight across both the L3-resident (nb/mn) and HBM-streaming (fr)
// address ranges. Tail handling via index clamp + select (no exec branches).
// fr is nontemporal so nb+mn (120 MB) stay resident in the 256 MiB L3.
__global__ __launch_bounds__(BLK) void pacmap_partial_kernel(
    const floatx4* __restrict__ nb, int n_n,
    const floatx4* __restrict__ mn, int n_m,
    const floatx4* __restrict__ fr, int n_f,
    float* __restrict__ ws) {

    const int tid = blockIdx.x * BLK + threadIdx.x;

    float s_n0 = 0.0f, s_n1 = 0.0f;
    float s_m0 = 0.0f;
    float s_f0 = 0.0f, s_f1 = 0.0f, s_f2 = 0.0f, s_f3 = 0.0f;

    // per-thread merged iteration count (differs by <=1 across lanes)
    const int rem_n = n_n - tid;
    const int rem_m = n_m - tid;
    const int rem_f = n_f - tid;
    int it_n = rem_n > 0 ? (rem_n + 2 * STRIDE - 1) / (2 * STRIDE) : 0;
    int it_m = rem_m > 0 ? (rem_m + STRIDE - 1) / STRIDE : 0;
    int it_f = rem_f > 0 ? (rem_f + 4 * STRIDE - 1) / (4 * STRIDE) : 0;
    int iters = max(it_n, max(it_m, it_f));

    int i_n = tid, i_m = tid, i_f = tid;

    for (int k = 0; k < iters; ++k) {
        const int in0 = i_n;
        const int in1 = i_n + STRIDE;
        const int im0 = i_m;
        const int if0 = i_f;
        const int if1 = i_f + STRIDE;
        const int if2 = i_f + 2 * STRIDE;
        const int if3 = i_f + 3 * STRIDE;

        // clamped addresses: always valid, always issued
        const int jn0 = min(in0, n_n - 1);
        const int jn1 = min(in1, n_n - 1);
        const int jm0 = min(im0, n_m - 1);
        const int jf0 = min(if0, n_f - 1);
        const int jf1 = min(if1, n_f - 1);
        const int jf2 = min(if2, n_f - 1);
        const int jf3 = min(if3, n_f - 1);

        // issue all 7 loads before any use
        floatx4 pf0 = __builtin_nontemporal_load(&fr[jf0]);
        floatx4 pf1 = __builtin_nontemporal_load(&fr[jf1]);
        floatx4 pf2 = __builtin_nontemporal_load(&fr[jf2]);
        floatx4 pf3 = __builtin_nontemporal_load(&fr[jf3]);
        floatx4 pn0 = nb[jn0];
        floatx4 pn1 = nb[jn1];
        floatx4 pm0 = mn[jm0];

        float dn0 = sqd1(pn0);
        float dn1 = sqd1(pn1);
        float dm0 = sqd1(pm0);
        float df0 = sqd1(pf0);
        float df1 = sqd1(pf1);
        float df2 = sqd1(pf2);
        float df3 = sqd1(pf3);

        s_n0 += (in0 < n_n) ? dn0 * frcp(10.0f + dn0) : 0.0f;
        s_n1 += (in1 < n_n) ? dn1 * frcp(10.0f + dn1) : 0.0f;
        s_m0 += (im0 < n_m) ? dm0 * frcp(10000.0f + dm0) : 0.0f;
        s_f0 += (if0 < n_f) ? frcp(1.0f + df0) : 0.0f;
        s_f1 += (if1 < n_f) ? frcp(1.0f + df1) : 0.0f;
        s_f2 += (if2 < n_f) ? frcp(1.0f + df2) : 0.0f;
        s_f3 += (if3 < n_f) ? frcp(1.0f + df3) : 0.0f;

        i_n += 2 * STRIDE;
        i_m += STRIDE;
        i_f += 4 * STRIDE;
    }

    float s_n = s_n0 + s_n1;
    float s_m = s_m0;
    float s_f = (s_f0 + s_f1) + (s_f2 + s_f3);

    // wave-64 shuffle reduction
    #pragma unroll
    for (int off = 32; off > 0; off >>= 1) {
        s_n += __shfl_down(s_n, off, 64);
        s_m += __shfl_down(s_m, off, 64);
        s_f += __shfl_down(s_f, off, 64);
    }

    __shared__ float sm[3][NWAVES];
    const int lane = threadIdx.x & 63;
    const int wid  = threadIdx.x >> 6;
    if (lane == 0) {
        sm[0][wid] = s_n;
        sm[1][wid] = s_m;
        sm[2][wid] = s_f;
    }
    __syncthreads();
    if (threadIdx.x == 0) {
        float a = 0.0f, b = 0.0f, c = 0.0f;
        #pragma unroll
        for (int i = 0; i < NWAVES; ++i) {
            a += sm[0][i];
            b += sm[1][i];
            c += sm[2][i];
        }
        ws[blockIdx.x]            = a;
        ws[GRID + blockIdx.x]     = b;
        ws[2 * GRID + blockIdx.x] = c;
    }
}

// Single-block finalize: reduce GRID partials per loss, apply phase weights.
__global__ __launch_bounds__(BLK) void pacmap_finalize_kernel(
    const float* __restrict__ ws,
    const int* __restrict__ iter_p,
    float* __restrict__ out) {

    float s_n = 0.0f, s_m = 0.0f, s_f = 0.0f;
    for (int i = threadIdx.x; i < GRID; i += BLK) {
        s_n += ws[i];
        s_m += ws[GRID + i];
        s_f += ws[2 * GRID + i];
    }

    #pragma unroll
    for (int off = 32; off > 0; off >>= 1) {
        s_n += __shfl_down(s_n, off, 64);
        s_m += __shfl_down(s_m, off, 64);
        s_f += __shfl_down(s_f, off, 64);
    }

    __shared__ float sm[3][NWAVES];
    const int lane = threadIdx.x & 63;
    const int wid  = threadIdx.x >> 6;
    if (lane == 0) {
        sm[0][wid] = s_n;
        sm[1][wid] = s_m;
        sm[2][wid] = s_f;
    }
    __syncthreads();
    if (threadIdx.x == 0) {
        float a = 0.0f, b = 0.0f, c = 0.0f;
        #pragma unroll
        for (int i = 0; i < NWAVES; ++i) {
            a += sm[0][i];
            b += sm[1][i];
            c += sm[2][i];
        }

        const int it = *iter_p;
        float w_n, w_m, w_f;
        if (it < 101) {
            const float frac = (0.0f - 1.0f) / (101.0f - 1.0f);
            w_n = 2.0f;
            w_m = 1000.0f * (1.0f - frac) + 3.0f * frac;
            w_f = 1.0f;
        } else if (it < 201) {
            w_n = 3.0f; w_m = 3.0f; w_f = 1.0f;
        } else {
            w_n = 1.0f; w_m = 0.0f; w_f = 1.0f;
        }
        out[0] = a * w_n + b * w_m + c * w_f;
    }
}

extern "C" void kernel_launch(void* const* d_in, const int* in_sizes, int n_in,
                              void* d_out, int out_size, void* d_ws, size_t ws_size,
                              hipStream_t stream) {
    const floatx4* nb = (const floatx4*)d_in[0];
    const floatx4* mn = (const floatx4*)d_in[1];
    const floatx4* fr = (const floatx4*)d_in[2];
    const int* iter_p = (const int*)d_in[3];

    const int n_n = in_sizes[0] / 4;
    const int n_m = in_sizes[1] / 4;
    const int n_f = in_sizes[2] / 4;

    float* ws  = (float*)d_ws;
    float* out = (float*)d_out;

    pacmap_partial_kernel<<<GRID, BLK, 0, stream>>>(nb, n_n, mn, n_m, fr, n_f, ws);
    pacmap_finalize_kernel<<<1, BLK, 0, stream>>>(ws, iter_p, out);
}